// Round 1
// baseline (77.560 us; speedup 1.0000x reference)
//
#include <hip/hip_runtime.h>
#include <hip/hip_bf16.h>

#define EPS 1e-6f

typedef __attribute__((ext_vector_type(8))) short bf16x8;
typedef __attribute__((ext_vector_type(4))) float f32x4;

__device__ inline unsigned short f2bf(float f) {
  __hip_bfloat16 h = __float2bfloat16(f);
  return *reinterpret_cast<unsigned short*>(&h);
}

// ---------------------------------------------------------------------------
// Kernel A: per-speaker precompute.
// Computes sums over M, ||sums||^2, per-utterance <d,sums>, ||d||^2.
// Writes: abf[i][d]  = bf16(dvec[i][d]/||dvec_i||)        (10240 x 768)
//         cnbf[n][d] = bf16(ctrd[n][d]/||ctrd_n||)        (1024 x 768)
//         simown[i]  = fp32 cosine(dvec_i, excl-centroid) (10240)
// ---------------------------------------------------------------------------
__global__ void __launch_bounds__(256) ge2e_pre(
    const float* __restrict__ dv, unsigned short* __restrict__ abf,
    unsigned short* __restrict__ cnbf, float* __restrict__ simown) {
  const int n = blockIdx.x, t = threadIdx.x;
  const float* base = dv + (size_t)n * 7680;
  float v[10][3];
  float sum[3] = {0.f, 0.f, 0.f};
#pragma unroll
  for (int m = 0; m < 10; ++m)
#pragma unroll
    for (int j = 0; j < 3; ++j) {
      float x = base[m * 768 + j * 256 + t];
      v[m][j] = x;
      sum[j] += x;
    }
  float part[21];
#pragma unroll
  for (int m = 0; m < 10; ++m) {
    float d = 0.f, q = 0.f;
#pragma unroll
    for (int j = 0; j < 3; ++j) {
      d += v[m][j] * sum[j];
      q += v[m][j] * v[m][j];
    }
    part[m] = d;
    part[10 + m] = q;
  }
  part[20] = sum[0] * sum[0] + sum[1] * sum[1] + sum[2] * sum[2];
  // wave butterfly reduce (64 lanes)
#pragma unroll
  for (int k = 0; k < 21; ++k) {
#pragma unroll
    for (int off = 32; off >= 1; off >>= 1) part[k] += __shfl_xor(part[k], off);
  }
  __shared__ float red[4][21];
  __shared__ float bc[21];
  const int lane = t & 63, wid = t >> 6;
  if (lane == 0) {
#pragma unroll
    for (int k = 0; k < 21; ++k) red[wid][k] = part[k];
  }
  __syncthreads();
  if (t < 21) bc[t] = red[0][t] + red[1][t] + red[2][t] + red[3][t];
  __syncthreads();
  const float ss = bc[20];
  // centroid = sums/10; cnorm = max(|sums|/10, eps) -> divide sums by max(|sums|, 10*eps)
  const float rc = 1.0f / fmaxf(sqrtf(ss), 10.0f * EPS);
#pragma unroll
  for (int j = 0; j < 3; ++j)
    cnbf[n * 768 + j * 256 + t] = f2bf(sum[j] * rc);
#pragma unroll
  for (int m = 0; m < 10; ++m) {
    float rd = 1.0f / fmaxf(sqrtf(bc[10 + m]), EPS);
#pragma unroll
    for (int j = 0; j < 3; ++j)
      abf[(size_t)(n * 10 + m) * 768 + j * 256 + t] = f2bf(v[m][j] * rd);
  }
  if (t < 10) {
    float dot = bc[t], sq = bc[10 + t];
    float dn = fmaxf(sqrtf(sq), EPS);
    float en = fmaxf(sqrtf(fmaxf(ss - 2.f * dot + sq, 0.f)) * (1.0f / 9.0f), EPS);
    simown[n * 10 + t] = ((dot - sq) * (1.0f / 9.0f)) / (dn * en);
  }
}

// ---------------------------------------------------------------------------
// Kernel B: bf16 MFMA GEMM (10240x1024x768) fused with diagonal replacement
// and per-row partial logsumexp over this block's 128 columns.
// m97 structure: 128x128 tile, BK=32, 4 waves (2x2), 4x4 frags/wave,
// global_load_lds width 16, single LDS buffer, 2 barriers/K-step.
// ---------------------------------------------------------------------------
__global__ void __launch_bounds__(256) ge2e_gemm(
    const unsigned short* __restrict__ abf, const unsigned short* __restrict__ cnbf,
    const float* __restrict__ simown, const float* __restrict__ wp,
    float2* __restrict__ lse) {
  __shared__ unsigned short As[128 * 32];
  __shared__ unsigned short Bs[128 * 32];
  const int t = threadIdx.x;
  const int lane = t & 63, wid = t >> 6;
  const int bx = blockIdx.x;
  const int rb = bx >> 3, cb = bx & 7;
  const int row0 = rb * 128, col0 = cb * 128;
  const int wr = wid >> 1, wc = wid & 1;
  const int l15 = lane & 15, lg = lane >> 4;

  f32x4 acc[4][4];
#pragma unroll
  for (int i = 0; i < 4; ++i)
#pragma unroll
    for (int j = 0; j < 4; ++j) acc[i][j] = (f32x4){0.f, 0.f, 0.f, 0.f};

  for (int kk = 0; kk < 768; kk += 32) {
    __syncthreads();  // previous iteration's ds_reads complete before overwrite
#pragma unroll
    for (int jj = 0; jj < 2; ++jj) {
      const int chunk = wid * 128 + jj * 64 + lane;  // 16B chunk index, 0..511
      const int r = chunk >> 2, kc = chunk & 3;
      const unsigned short* srcA = abf + (size_t)(row0 + r) * 768 + kk + kc * 8;
      unsigned short* dstA = &As[wid * 1024 + jj * 512];  // wave-uniform base
      __builtin_amdgcn_global_load_lds(
          (const __attribute__((address_space(1))) unsigned int*)srcA,
          (__attribute__((address_space(3))) unsigned int*)dstA, 16, 0, 0);
      const unsigned short* srcB = cnbf + (size_t)(col0 + r) * 768 + kk + kc * 8;
      unsigned short* dstB = &Bs[wid * 1024 + jj * 512];
      __builtin_amdgcn_global_load_lds(
          (const __attribute__((address_space(1))) unsigned int*)srcB,
          (__attribute__((address_space(3))) unsigned int*)dstB, 16, 0, 0);
    }
    __syncthreads();  // drains vmcnt: staged tile visible to all waves
    bf16x8 af[4], bfr[4];
#pragma unroll
    for (int i = 0; i < 4; ++i)
      af[i] = *(const bf16x8*)&As[(wr * 64 + i * 16 + l15) * 32 + lg * 8];
#pragma unroll
    for (int j = 0; j < 4; ++j)
      bfr[j] = *(const bf16x8*)&Bs[(wc * 64 + j * 16 + l15) * 32 + lg * 8];
#pragma unroll
    for (int i = 0; i < 4; ++i)
#pragma unroll
      for (int j = 0; j < 4; ++j)
        acc[i][j] = __builtin_amdgcn_mfma_f32_16x16x32_bf16(af[i], bfr[j], acc[i][j], 0, 0, 0);
  }

  // Epilogue: logits = w*cos (bias b cancels in log_softmax - pick), diagonal
  // replaced by fp32 sim_own; per-row (max, expsum) over this wave's 64 cols,
  // then written as a partial for kernel C.
  const float wv = wp[0];
  const int R0 = row0 + wr * 64, C0 = col0 + wc * 64;
#pragma unroll
  for (int i = 0; i < 4; ++i) {
#pragma unroll
    for (int r = 0; r < 4; ++r) {
      const int grow = R0 + i * 16 + lg * 4 + r;
      const int ownc = grow / 10;  // own speaker column
      float vj[4];
#pragma unroll
      for (int j = 0; j < 4; ++j) {
        const int gcol = C0 + j * 16 + l15;
        float vv = wv * acc[i][j][r];
        if (gcol == ownc) vv = wv * simown[grow];
        vj[j] = vv;
      }
      float mx = fmaxf(fmaxf(vj[0], vj[1]), fmaxf(vj[2], vj[3]));
#pragma unroll
      for (int off = 1; off < 16; off <<= 1) mx = fmaxf(mx, __shfl_xor(mx, off, 16));
      float sm = __expf(vj[0] - mx) + __expf(vj[1] - mx) +
                 __expf(vj[2] - mx) + __expf(vj[3] - mx);
#pragma unroll
      for (int off = 1; off < 16; off <<= 1) sm += __shfl_xor(sm, off, 16);
      if (l15 == 0) lse[(size_t)grow * 16 + cb * 2 + wc] = make_float2(mx, sm);
    }
  }
}

// ---------------------------------------------------------------------------
// Kernel C: combine 16 (m,s) partials per row, loss = m + log(s) - w*simown,
// sum all 10240 losses into d_out.
// ---------------------------------------------------------------------------
__global__ void __launch_bounds__(256) ge2e_final(
    const float2* __restrict__ lse, const float* __restrict__ simown,
    const float* __restrict__ wp, float* __restrict__ out) {
  const int i = blockIdx.x * 256 + threadIdx.x;  // 0..10239
  const float wv = wp[0];
  float2 p[16];
  float m = -1e30f;
#pragma unroll
  for (int k = 0; k < 16; ++k) {
    p[k] = lse[(size_t)i * 16 + k];
    m = fmaxf(m, p[k].x);
  }
  float s = 0.f;
#pragma unroll
  for (int k = 0; k < 16; ++k) s += p[k].y * __expf(p[k].x - m);
  float loss = m + logf(s) - wv * simown[i];
#pragma unroll
  for (int off = 32; off >= 1; off >>= 1) loss += __shfl_xor(loss, off);
  __shared__ float red[4];
  const int lane = threadIdx.x & 63, wid = threadIdx.x >> 6;
  if (lane == 0) red[wid] = loss;
  __syncthreads();
  if (threadIdx.x == 0) atomicAdd(out, red[0] + red[1] + red[2] + red[3]);
}

extern "C" void kernel_launch(void* const* d_in, const int* in_sizes, int n_in,
                              void* d_out, int out_size, void* d_ws, size_t ws_size,
                              hipStream_t stream) {
  (void)in_sizes; (void)n_in; (void)out_size; (void)ws_size;
  const float* dv = (const float*)d_in[0];
  const float* wp = (const float*)d_in[1];
  // d_in[2] (bias b) cancels exactly in -log_softmax[own]; unused.

  // workspace layout (16B-aligned offsets)
  unsigned short* abf = (unsigned short*)d_ws;                        // 15,728,640 B
  unsigned short* cnbf = (unsigned short*)((char*)d_ws + 15728640);   //  1,572,864 B
  float* simown = (float*)((char*)d_ws + 17301504);                   //     40,960 B
  float2* lse = (float2*)((char*)d_ws + 17342464);                    //  1,310,720 B
  float* out = (float*)d_out;

  hipMemsetAsync(out, 0, sizeof(float), stream);
  ge2e_pre<<<1024, 256, 0, stream>>>(dv, abf, cnbf, simown);
  ge2e_gemm<<<640, 256, 0, stream>>>(abf, cnbf, simown, wp, lse);
  ge2e_final<<<40, 256, 0, stream>>>(lse, simown, wp, out);
}

// Round 2
// 57.161 us; speedup vs baseline: 1.3569x; 1.3569x over previous
//
#include <hip/hip_runtime.h>
#include <hip/hip_bf16.h>

#define EPS 1e-6f

typedef __attribute__((ext_vector_type(8))) short bf16x8;
typedef __attribute__((ext_vector_type(4))) float f32x4;

__device__ inline unsigned short f2bf(float f) {
  __hip_bfloat16 h = __float2bfloat16(f);
  return *reinterpret_cast<unsigned short*>(&h);
}

// ---------------------------------------------------------------------------
// Kernel A: per-speaker precompute.
// Computes sums over M, ||sums||^2, per-utterance <d,sums>, ||d||^2.
// Writes: abf[i][d]  = bf16(dvec[i][d]/||dvec_i||)        (10240 x 768)
//         cnbf[n][d] = bf16(ctrd[n][d]/||ctrd_n||)        (1024 x 768)
//         simown[i]  = fp32 cosine(dvec_i, excl-centroid) (10240)
// ---------------------------------------------------------------------------
__global__ void __launch_bounds__(256) ge2e_pre(
    const float* __restrict__ dv, unsigned short* __restrict__ abf,
    unsigned short* __restrict__ cnbf, float* __restrict__ simown) {
  const int n = blockIdx.x, t = threadIdx.x;
  const float* base = dv + (size_t)n * 7680;
  float v[10][3];
  float sum[3] = {0.f, 0.f, 0.f};
#pragma unroll
  for (int m = 0; m < 10; ++m)
#pragma unroll
    for (int j = 0; j < 3; ++j) {
      float x = base[m * 768 + j * 256 + t];
      v[m][j] = x;
      sum[j] += x;
    }
  float part[21];
#pragma unroll
  for (int m = 0; m < 10; ++m) {
    float d = 0.f, q = 0.f;
#pragma unroll
    for (int j = 0; j < 3; ++j) {
      d += v[m][j] * sum[j];
      q += v[m][j] * v[m][j];
    }
    part[m] = d;
    part[10 + m] = q;
  }
  part[20] = sum[0] * sum[0] + sum[1] * sum[1] + sum[2] * sum[2];
  // wave butterfly reduce (64 lanes)
#pragma unroll
  for (int k = 0; k < 21; ++k) {
#pragma unroll
    for (int off = 32; off >= 1; off >>= 1) part[k] += __shfl_xor(part[k], off);
  }
  __shared__ float red[4][21];
  __shared__ float bc[21];
  const int lane = t & 63, wid = t >> 6;
  if (lane == 0) {
#pragma unroll
    for (int k = 0; k < 21; ++k) red[wid][k] = part[k];
  }
  __syncthreads();
  if (t < 21) bc[t] = red[0][t] + red[1][t] + red[2][t] + red[3][t];
  __syncthreads();
  const float ss = bc[20];
  const float rc = 1.0f / fmaxf(sqrtf(ss), 10.0f * EPS);
#pragma unroll
  for (int j = 0; j < 3; ++j)
    cnbf[n * 768 + j * 256 + t] = f2bf(sum[j] * rc);
#pragma unroll
  for (int m = 0; m < 10; ++m) {
    float rd = 1.0f / fmaxf(sqrtf(bc[10 + m]), EPS);
#pragma unroll
    for (int j = 0; j < 3; ++j)
      abf[(size_t)(n * 10 + m) * 768 + j * 256 + t] = f2bf(v[m][j] * rd);
  }
  if (t < 10) {
    float dot = bc[t], sq = bc[10 + t];
    float dn = fmaxf(sqrtf(sq), EPS);
    float en = fmaxf(sqrtf(fmaxf(ss - 2.f * dot + sq, 0.f)) * (1.0f / 9.0f), EPS);
    simown[n * 10 + t] = ((dot - sq) * (1.0f / 9.0f)) / (dn * en);
  }
}

// ---------------------------------------------------------------------------
// Kernel B: bf16 MFMA GEMM (10240x1024x768) fused with diagonal replacement
// and per-row partial logsumexp over this block's 128 columns.
// Round-2 structure: 128x128 tile, BK=32, 4 waves (2x2), DOUBLE-buffered LDS
// with prefetch-next-tile-before-compute (T3 minimal 2-phase: raw s_barrier +
// one inline-asm vmcnt(0) per tile, no __syncthreads drain), plus bijective
// XCD swizzle (640 = 8 XCDs x 80) so each XCD's L2 holds its A-strips + all
// of B (~3.5 MB working set < 4 MB L2).
// ---------------------------------------------------------------------------
__global__ void __launch_bounds__(256) ge2e_gemm(
    const unsigned short* __restrict__ abf, const unsigned short* __restrict__ cnbf,
    const float* __restrict__ simown, const float* __restrict__ wp,
    float2* __restrict__ lse) {
  __shared__ unsigned short As[2][128 * 32];
  __shared__ unsigned short Bs[2][128 * 32];
  const int t = threadIdx.x;
  const int lane = t & 63, wid = t >> 6;
  // bijective XCD swizzle: bx%8 = XCD id; give each XCD 80 contiguous wgs
  const int bx = blockIdx.x;
  const int wg = (bx & 7) * 80 + (bx >> 3);
  const int rb = wg >> 3, cb = wg & 7;
  const int row0 = rb * 128, col0 = cb * 128;
  const int wr = wid >> 1, wc = wid & 1;
  const int l15 = lane & 15, lg = lane >> 4;

  f32x4 acc[4][4];
#pragma unroll
  for (int i = 0; i < 4; ++i)
#pragma unroll
    for (int j = 0; j < 4; ++j) acc[i][j] = (f32x4){0.f, 0.f, 0.f, 0.f};

  // stage one 128x32 A-tile + 128x32 B-tile into buffer `buf` (4 loads/wave)
  auto STAGE = [&](int buf, int kk) {
#pragma unroll
    for (int jj = 0; jj < 2; ++jj) {
      const int chunk = wid * 128 + jj * 64 + lane;  // 16B chunk idx, 0..511
      const int r = chunk >> 2, kc = chunk & 3;
      const unsigned short* srcA = abf + (size_t)(row0 + r) * 768 + kk + kc * 8;
      unsigned short* dstA = &As[buf][wid * 1024 + jj * 512];  // wave-uniform base
      __builtin_amdgcn_global_load_lds(
          (const __attribute__((address_space(1))) unsigned int*)srcA,
          (__attribute__((address_space(3))) unsigned int*)dstA, 16, 0, 0);
      const unsigned short* srcB = cnbf + (size_t)(col0 + r) * 768 + kk + kc * 8;
      unsigned short* dstB = &Bs[buf][wid * 1024 + jj * 512];
      __builtin_amdgcn_global_load_lds(
          (const __attribute__((address_space(1))) unsigned int*)srcB,
          (__attribute__((address_space(3))) unsigned int*)dstB, 16, 0, 0);
    }
  };
  auto COMPUTE = [&](int buf) {
    bf16x8 af[4], bfr[4];
#pragma unroll
    for (int i = 0; i < 4; ++i)
      af[i] = *(const bf16x8*)&As[buf][(wr * 64 + i * 16 + l15) * 32 + lg * 8];
#pragma unroll
    for (int j = 0; j < 4; ++j)
      bfr[j] = *(const bf16x8*)&Bs[buf][(wc * 64 + j * 16 + l15) * 32 + lg * 8];
#pragma unroll
    for (int i = 0; i < 4; ++i)
#pragma unroll
      for (int j = 0; j < 4; ++j)
        acc[i][j] = __builtin_amdgcn_mfma_f32_16x16x32_bf16(af[i], bfr[j], acc[i][j], 0, 0, 0);
  };

  // prologue
  STAGE(0, 0);
  asm volatile("s_waitcnt vmcnt(0)" ::: "memory");
  __builtin_amdgcn_s_barrier();
  int cur = 0;
  // main loop: prefetch t+1 while computing t; one vmcnt drain + barrier/tile
  for (int tt = 0; tt < 23; ++tt) {
    STAGE(cur ^ 1, (tt + 1) * 32);
    COMPUTE(cur);  // compiler inserts lgkmcnt waits for ds_read->MFMA deps
    asm volatile("s_waitcnt vmcnt(0)" ::: "memory");  // prefetched tile landed
    __builtin_amdgcn_s_barrier();
    cur ^= 1;
  }
  COMPUTE(cur);  // last tile, no prefetch

  // Epilogue: logits = w*cos (bias b cancels in log_softmax - pick), diagonal
  // replaced by fp32 sim_own; per-row (max, expsum) over this wave's 64 cols.
  const float wv = wp[0];
  const int R0 = row0 + wr * 64, C0 = col0 + wc * 64;
#pragma unroll
  for (int i = 0; i < 4; ++i) {
#pragma unroll
    for (int r = 0; r < 4; ++r) {
      const int grow = R0 + i * 16 + lg * 4 + r;
      const int ownc = grow / 10;  // own speaker column
      float vj[4];
#pragma unroll
      for (int j = 0; j < 4; ++j) {
        const int gcol = C0 + j * 16 + l15;
        float vv = wv * acc[i][j][r];
        if (gcol == ownc) vv = wv * simown[grow];
        vj[j] = vv;
      }
      float mx = fmaxf(fmaxf(vj[0], vj[1]), fmaxf(vj[2], vj[3]));
#pragma unroll
      for (int off = 1; off < 16; off <<= 1) mx = fmaxf(mx, __shfl_xor(mx, off, 16));
      float sm = __expf(vj[0] - mx) + __expf(vj[1] - mx) +
                 __expf(vj[2] - mx) + __expf(vj[3] - mx);
#pragma unroll
      for (int off = 1; off < 16; off <<= 1) sm += __shfl_xor(sm, off, 16);
      if (l15 == 0) lse[(size_t)grow * 16 + cb * 2 + wc] = make_float2(mx, sm);
    }
  }
}

// ---------------------------------------------------------------------------
// Kernel C: combine 16 (m,s) partials per row, loss = m + log(s) - w*simown,
// sum all 10240 losses into d_out.
// ---------------------------------------------------------------------------
__global__ void __launch_bounds__(256) ge2e_final(
    const float2* __restrict__ lse, const float* __restrict__ simown,
    const float* __restrict__ wp, float* __restrict__ out) {
  const int i = blockIdx.x * 256 + threadIdx.x;  // 0..10239
  const float wv = wp[0];
  float2 p[16];
  float m = -1e30f;
#pragma unroll
  for (int k = 0; k < 16; ++k) {
    p[k] = lse[(size_t)i * 16 + k];
    m = fmaxf(m, p[k].x);
  }
  float s = 0.f;
#pragma unroll
  for (int k = 0; k < 16; ++k) s += p[k].y * __expf(p[k].x - m);
  float loss = m + logf(s) - wv * simown[i];
#pragma unroll
  for (int off = 32; off >= 1; off >>= 1) loss += __shfl_xor(loss, off);
  __shared__ float red[4];
  const int lane = threadIdx.x & 63, wid = threadIdx.x >> 6;
  if (lane == 0) red[wid] = loss;
  __syncthreads();
  if (threadIdx.x == 0) atomicAdd(out, red[0] + red[1] + red[2] + red[3]);
}

extern "C" void kernel_launch(void* const* d_in, const int* in_sizes, int n_in,
                              void* d_out, int out_size, void* d_ws, size_t ws_size,
                              hipStream_t stream) {
  (void)in_sizes; (void)n_in; (void)out_size; (void)ws_size;
  const float* dv = (const float*)d_in[0];
  const float* wp = (const float*)d_in[1];
  // d_in[2] (bias b) cancels exactly in -log_softmax[own]; unused.

  unsigned short* abf = (unsigned short*)d_ws;                        // 15,728,640 B
  unsigned short* cnbf = (unsigned short*)((char*)d_ws + 15728640);   //  1,572,864 B
  float* simown = (float*)((char*)d_ws + 17301504);                   //     40,960 B
  float2* lse = (float2*)((char*)d_ws + 17342464);                    //  1,310,720 B
  float* out = (float*)d_out;

  hipMemsetAsync(out, 0, sizeof(float), stream);
  ge2e_pre<<<1024, 256, 0, stream>>>(dv, abf, cnbf, simown);
  ge2e_gemm<<<640, 256, 0, stream>>>(abf, cnbf, simown, wp, lse);
  ge2e_final<<<40, 256, 0, stream>>>(lse, simown, wp, out);
}

// Round 3
// 56.989 us; speedup vs baseline: 1.3610x; 1.0030x over previous
//
#include <hip/hip_runtime.h>
#include <hip/hip_bf16.h>

#define EPS 1e-6f

typedef __attribute__((ext_vector_type(8))) short bf16x8;
typedef __attribute__((ext_vector_type(4))) float f32x4;

__device__ inline unsigned short f2bf(float f) {
  __hip_bfloat16 h = __float2bfloat16(f);
  return *reinterpret_cast<unsigned short*>(&h);
}

// ---------------------------------------------------------------------------
// Kernel A: per-speaker precompute (192 threads, float4-vectorized).
// Computes sums over M, ||sums||^2, per-utterance <d,sums>, ||d||^2.
// Writes: abf[i][d]  = bf16(dvec[i][d]/||dvec_i||)        (10240 x 768)
//         cnbf[n][d] = bf16(ctrd[n][d]/||ctrd_n||)        (1024 x 768)
//         simown[i]  = fp32 cosine(dvec_i, excl-centroid) (10240)
// ---------------------------------------------------------------------------
__global__ void __launch_bounds__(192) ge2e_pre(
    const float* __restrict__ dv, unsigned short* __restrict__ abf,
    unsigned short* __restrict__ cnbf, float* __restrict__ simown) {
  const int n = blockIdx.x, t = threadIdx.x;  // t in [0,192): owns dims 4t..4t+3
  const float* base = dv + (size_t)n * 7680;
  float4 v[10];
  float4 s4 = make_float4(0.f, 0.f, 0.f, 0.f);
#pragma unroll
  for (int m = 0; m < 10; ++m) {
    v[m] = *reinterpret_cast<const float4*>(&base[m * 768 + 4 * t]);
    s4.x += v[m].x; s4.y += v[m].y; s4.z += v[m].z; s4.w += v[m].w;
  }
  float part[21];
#pragma unroll
  for (int m = 0; m < 10; ++m) {
    part[m]      = v[m].x * s4.x + v[m].y * s4.y + v[m].z * s4.z + v[m].w * s4.w;
    part[10 + m] = v[m].x * v[m].x + v[m].y * v[m].y + v[m].z * v[m].z + v[m].w * v[m].w;
  }
  part[20] = s4.x * s4.x + s4.y * s4.y + s4.z * s4.z + s4.w * s4.w;
  // wave butterfly reduce (64 lanes)
#pragma unroll
  for (int k = 0; k < 21; ++k) {
#pragma unroll
    for (int off = 32; off >= 1; off >>= 1) part[k] += __shfl_xor(part[k], off);
  }
  __shared__ float red[3][21];
  __shared__ float bc[21];
  const int lane = t & 63, wid = t >> 6;
  if (lane == 0) {
#pragma unroll
    for (int k = 0; k < 21; ++k) red[wid][k] = part[k];
  }
  __syncthreads();
  if (t < 21) bc[t] = red[0][t] + red[1][t] + red[2][t];
  __syncthreads();
  const float ss = bc[20];
  // centroid = sums/10; cnorm = max(|ctrd|, eps) -> divide sums by max(|sums|, 10*eps)
  const float rc = 1.0f / fmaxf(sqrtf(ss), 10.0f * EPS);
  {
    short4 c;
    c.x = (short)f2bf(s4.x * rc); c.y = (short)f2bf(s4.y * rc);
    c.z = (short)f2bf(s4.z * rc); c.w = (short)f2bf(s4.w * rc);
    *reinterpret_cast<short4*>(&cnbf[n * 768 + 4 * t]) = c;
  }
#pragma unroll
  for (int m = 0; m < 10; ++m) {
    float rd = 1.0f / fmaxf(sqrtf(bc[10 + m]), EPS);
    short4 a;
    a.x = (short)f2bf(v[m].x * rd); a.y = (short)f2bf(v[m].y * rd);
    a.z = (short)f2bf(v[m].z * rd); a.w = (short)f2bf(v[m].w * rd);
    *reinterpret_cast<short4*>(&abf[(size_t)(n * 10 + m) * 768 + 4 * t]) = a;
  }
  if (t < 10) {
    float dot = bc[t], sq = bc[10 + t];
    float dn = fmaxf(sqrtf(sq), EPS);
    float en = fmaxf(sqrtf(fmaxf(ss - 2.f * dot + sq, 0.f)) * (1.0f / 9.0f), EPS);
    simown[n * 10 + t] = ((dot - sq) * (1.0f / 9.0f)) / (dn * en);
  }
}

// ---------------------------------------------------------------------------
// Kernel B: bf16 MFMA GEMM (10240x1024x768) fused with diagonal replacement
// and per-row partial logsumexp over this block's 128 columns.
// Round-3 structure: 128x128 tile, BK=32, 4 waves (2x2), TRIPLE-buffered LDS
// with depth-2 prefetch and COUNTED vmcnt(4) (T4: never drain to 0 in the
// main loop -- 2 tiles stay in flight, load latency amortizes over 2 tiles
// of MFMA). One raw s_barrier per K-step. Bijective XCD swizzle (640 = 8x80)
// keeps each XCD's A-strips + all of B inside its 4 MB L2.
// ---------------------------------------------------------------------------
__global__ void __launch_bounds__(256) ge2e_gemm(
    const unsigned short* __restrict__ abf, const unsigned short* __restrict__ cnbf,
    const float* __restrict__ simown, const float* __restrict__ wp,
    float2* __restrict__ lse) {
  __shared__ unsigned short As[3][128 * 32];
  __shared__ unsigned short Bs[3][128 * 32];
  const int t = threadIdx.x;
  const int lane = t & 63, wid = t >> 6;
  // bijective XCD swizzle: bx%8 = XCD id; give each XCD 80 contiguous wgs
  const int bx = blockIdx.x;
  const int wg = (bx & 7) * 80 + (bx >> 3);
  const int rb = wg >> 3, cb = wg & 7;
  const int row0 = rb * 128, col0 = cb * 128;
  const int wr = wid >> 1, wc = wid & 1;
  const int l15 = lane & 15, lg = lane >> 4;

  f32x4 acc[4][4];
#pragma unroll
  for (int i = 0; i < 4; ++i)
#pragma unroll
    for (int j = 0; j < 4; ++j) acc[i][j] = (f32x4){0.f, 0.f, 0.f, 0.f};

  // stage one 128x32 A-tile + 128x32 B-tile into buffer `buf` (4 loads/wave)
  auto STAGE = [&](int buf, int kk) {
#pragma unroll
    for (int jj = 0; jj < 2; ++jj) {
      const int chunk = wid * 128 + jj * 64 + lane;  // 16B chunk idx, 0..511
      const int r = chunk >> 2, kc = chunk & 3;
      const unsigned short* srcA = abf + (size_t)(row0 + r) * 768 + kk + kc * 8;
      unsigned short* dstA = &As[buf][wid * 1024 + jj * 512];  // wave-uniform base
      __builtin_amdgcn_global_load_lds(
          (const __attribute__((address_space(1))) unsigned int*)srcA,
          (__attribute__((address_space(3))) unsigned int*)dstA, 16, 0, 0);
      const unsigned short* srcB = cnbf + (size_t)(col0 + r) * 768 + kk + kc * 8;
      unsigned short* dstB = &Bs[buf][wid * 1024 + jj * 512];
      __builtin_amdgcn_global_load_lds(
          (const __attribute__((address_space(1))) unsigned int*)srcB,
          (__attribute__((address_space(3))) unsigned int*)dstB, 16, 0, 0);
    }
  };
  auto COMPUTE = [&](int buf) {
    bf16x8 af[4], bfr[4];
#pragma unroll
    for (int i = 0; i < 4; ++i)
      af[i] = *(const bf16x8*)&As[buf][(wr * 64 + i * 16 + l15) * 32 + lg * 8];
#pragma unroll
    for (int j = 0; j < 4; ++j)
      bfr[j] = *(const bf16x8*)&Bs[buf][(wc * 64 + j * 16 + l15) * 32 + lg * 8];
#pragma unroll
    for (int i = 0; i < 4; ++i)
#pragma unroll
      for (int j = 0; j < 4; ++j)
        acc[i][j] = __builtin_amdgcn_mfma_f32_16x16x32_bf16(af[i], bfr[j], acc[i][j], 0, 0, 0);
  };

  // prologue: 2 tiles in flight (8 outstanding global_load_lds per wave)
  STAGE(0, 0);
  STAGE(1, 32);
  int b0 = 0, b1 = 1, b2 = 2;
  // main loop over tiles 0..21: wait only for the OLDEST tile (vmcnt(4)),
  // keep the next one in flight, issue tile tt+2 after the barrier.
  for (int tt = 0; tt < 22; ++tt) {
    asm volatile("s_waitcnt vmcnt(4)" ::: "memory");  // tile tt landed
    __builtin_amdgcn_s_barrier();                     // ...for ALL waves
    STAGE(b2, (tt + 2) * 32);  // overwrites buffer read at tt-1 (safe: those
                               // ds_reads completed before this barrier)
    COMPUTE(b0);
    int tmp = b0; b0 = b1; b1 = b2; b2 = tmp;
  }
  // epilogue tiles 22, 23
  asm volatile("s_waitcnt vmcnt(4)" ::: "memory");
  __builtin_amdgcn_s_barrier();
  COMPUTE(b0);
  asm volatile("s_waitcnt vmcnt(0)" ::: "memory");
  __builtin_amdgcn_s_barrier();
  COMPUTE(b1);

  // Epilogue: logits = w*cos (bias b cancels in log_softmax - pick), diagonal
  // replaced by fp32 sim_own; per-row (max, expsum) over this wave's 64 cols.
  const float wv = wp[0];
  const int R0 = row0 + wr * 64, C0 = col0 + wc * 64;
#pragma unroll
  for (int i = 0; i < 4; ++i) {
#pragma unroll
    for (int r = 0; r < 4; ++r) {
      const int grow = R0 + i * 16 + lg * 4 + r;
      const int ownc = grow / 10;  // own speaker column
      float vj[4];
#pragma unroll
      for (int j = 0; j < 4; ++j) {
        const int gcol = C0 + j * 16 + l15;
        float vv = wv * acc[i][j][r];
        if (gcol == ownc) vv = wv * simown[grow];
        vj[j] = vv;
      }
      float mx = fmaxf(fmaxf(vj[0], vj[1]), fmaxf(vj[2], vj[3]));
#pragma unroll
      for (int off = 1; off < 16; off <<= 1) mx = fmaxf(mx, __shfl_xor(mx, off, 16));
      float sm = __expf(vj[0] - mx) + __expf(vj[1] - mx) +
                 __expf(vj[2] - mx) + __expf(vj[3] - mx);
#pragma unroll
      for (int off = 1; off < 16; off <<= 1) sm += __shfl_xor(sm, off, 16);
      if (l15 == 0) lse[(size_t)grow * 16 + cb * 2 + wc] = make_float2(mx, sm);
    }
  }
}

// ---------------------------------------------------------------------------
// Kernel C: combine 16 (m,s) partials per row, loss = m + log(s) - w*simown,
// sum all 10240 losses into d_out.
// ---------------------------------------------------------------------------
__global__ void __launch_bounds__(256) ge2e_final(
    const float2* __restrict__ lse, const float* __restrict__ simown,
    const float* __restrict__ wp, float* __restrict__ out) {
  const int i = blockIdx.x * 256 + threadIdx.x;  // 0..10239
  const float wv = wp[0];
  float2 p[16];
  float m = -1e30f;
#pragma unroll
  for (int k = 0; k < 16; ++k) {
    p[k] = lse[(size_t)i * 16 + k];
    m = fmaxf(m, p[k].x);
  }
  float s = 0.f;
#pragma unroll
  for (int k = 0; k < 16; ++k) s += p[k].y * __expf(p[k].x - m);
  float loss = m + logf(s) - wv * simown[i];
#pragma unroll
  for (int off = 32; off >= 1; off >>= 1) loss += __shfl_xor(loss, off);
  __shared__ float red[4];
  const int lane = threadIdx.x & 63, wid = threadIdx.x >> 6;
  if (lane == 0) red[wid] = loss;
  __syncthreads();
  if (threadIdx.x == 0) atomicAdd(out, red[0] + red[1] + red[2] + red[3]);
}

extern "C" void kernel_launch(void* const* d_in, const int* in_sizes, int n_in,
                              void* d_out, int out_size, void* d_ws, size_t ws_size,
                              hipStream_t stream) {
  (void)in_sizes; (void)n_in; (void)out_size; (void)ws_size;
  const float* dv = (const float*)d_in[0];
  const float* wp = (const float*)d_in[1];
  // d_in[2] (bias b) cancels exactly in -log_softmax[own]; unused.

  unsigned short* abf = (unsigned short*)d_ws;                        // 15,728,640 B
  unsigned short* cnbf = (unsigned short*)((char*)d_ws + 15728640);   //  1,572,864 B
  float* simown = (float*)((char*)d_ws + 17301504);                   //     40,960 B
  float2* lse = (float2*)((char*)d_ws + 17342464);                    //  1,310,720 B
  float* out = (float*)d_out;

  hipMemsetAsync(out, 0, sizeof(float), stream);
  ge2e_pre<<<1024, 192, 0, stream>>>(dv, abf, cnbf, simown);
  ge2e_gemm<<<640, 256, 0, stream>>>(abf, cnbf, simown, wp, lse);
  ge2e_final<<<40, 256, 0, stream>>>(lse, simown, wp, out);
}